// Round 1
// baseline (597.246 us; speedup 1.0000x reference)
//
#include <hip/hip_runtime.h>

// Mamba selective scan, fp32. Shapes: u,delta,z:(4,2048,2048) A:(2048,16)
// B,C:(4,16,2048) D:(2048,). Output y:(4,2048,2048).
// 3-pass chunked scan: chunk operator is (S=sum dt, q=local scan), since
// prod_t exp(dt_t*A[n]) == exp(A[n]*sum_t dt_t).

#define BATCHSZ 4
#define DIN 2048
#define NSTATE 16
#define SEQ 2048
#define NCH (BATCHSZ * DIN)     // 8192 channels
#define NCHUNK 16
#define LC (SEQ / NCHUNK)       // 128
#define REC 17                  // 16 q-values + 1 dt-sum
#define L2E 1.44269504f

__device__ __forceinline__ float softplus_f(float v) {
    // log(1+exp(v)) via exp2/log2 hardware ops
    float e = __builtin_amdgcn_exp2f(v * L2E);
    return 0.69314718f * __builtin_amdgcn_logf(1.0f + e);
}

__device__ __forceinline__ float silu_f(float v) {
    // v * sigmoid(v)
    float s = __builtin_amdgcn_rcpf(1.0f + __builtin_amdgcn_exp2f(-v * L2E));
    return v * s;
}

__device__ __forceinline__ float comp4(const float4& f, int k) {
    return k == 0 ? f.x : k == 1 ? f.y : k == 2 ? f.z : f.w;
}

// Pass 1: per (b,d,chunk) local scan from zero state -> (q[16], S)
__global__ __launch_bounds__(256) void k_pass1(
        const float* __restrict__ u, const float* __restrict__ delta,
        const float* __restrict__ A, const float* __restrict__ Bm,
        float* __restrict__ ws) {
    int tid = blockIdx.x * 256 + threadIdx.x;
    int bd = tid & (NCH - 1);        // d fastest -> B loads wave-uniform
    int c  = tid >> 13;              // NCH = 2^13
    int b  = bd >> 11;               // DIN = 2^11
    int d  = bd & (DIN - 1);

    float A2[NSTATE];
    const float* Ar = A + d * NSTATE;
    #pragma unroll
    for (int n = 0; n < NSTATE; ++n) A2[n] = Ar[n] * L2E;

    float x[NSTATE];
    #pragma unroll
    for (int n = 0; n < NSTATE; ++n) x[n] = 0.0f;
    float S = 0.0f;

    size_t base = (size_t)bd * SEQ + (size_t)c * LC;
    const float4* u4 = (const float4*)(u + base);
    const float4* d4 = (const float4*)(delta + base);
    const float* Bp = Bm + (size_t)b * NSTATE * SEQ + (size_t)c * LC;

    for (int t4 = 0; t4 < LC / 4; ++t4) {
        float4 uu = u4[t4];
        float4 dd = d4[t4];
        #pragma unroll
        for (int k = 0; k < 4; ++k) {
            float dt = softplus_f(comp4(dd, k));
            S += dt;
            float du = dt * comp4(uu, k);
            int t = t4 * 4 + k;
            #pragma unroll
            for (int n = 0; n < NSTATE; ++n) {
                float dA = __builtin_amdgcn_exp2f(A2[n] * dt);
                x[n] = x[n] * dA + du * Bp[n * SEQ + t];
            }
        }
    }
    float* rec = ws + ((size_t)bd * NCHUNK + c) * REC;
    #pragma unroll
    for (int n = 0; n < NSTATE; ++n) rec[n] = x[n];
    rec[NSTATE] = S;
}

// Pass 2: per (b,d) combine chunk operators sequentially; overwrite q with
// the chunk's INITIAL state (prefix), in place.
__global__ __launch_bounds__(256) void k_pass2(
        const float* __restrict__ A, float* __restrict__ ws) {
    int bd = blockIdx.x * 256 + threadIdx.x;
    int d = bd & (DIN - 1);

    float A2[NSTATE];
    const float* Ar = A + d * NSTATE;
    #pragma unroll
    for (int n = 0; n < NSTATE; ++n) A2[n] = Ar[n] * L2E;

    float x[NSTATE];
    #pragma unroll
    for (int n = 0; n < NSTATE; ++n) x[n] = 0.0f;

    for (int c = 0; c < NCHUNK; ++c) {
        float* rec = ws + ((size_t)bd * NCHUNK + c) * REC;
        float S = rec[NSTATE];
        #pragma unroll
        for (int n = 0; n < NSTATE; ++n) {
            float q = rec[n];
            float P = __builtin_amdgcn_exp2f(A2[n] * S);
            rec[n] = x[n];               // initial state for chunk c
            x[n] = x[n] * P + q;
        }
    }
}

// Pass 3: per (b,d,chunk) rescan from the chunk's initial state; emit y.
__global__ __launch_bounds__(256) void k_pass3(
        const float* __restrict__ u, const float* __restrict__ delta,
        const float* __restrict__ A, const float* __restrict__ Bm,
        const float* __restrict__ Cm, const float* __restrict__ Dv,
        const float* __restrict__ z, const float* __restrict__ ws,
        float* __restrict__ out) {
    int tid = blockIdx.x * 256 + threadIdx.x;
    int bd = tid & (NCH - 1);
    int c  = tid >> 13;
    int b  = bd >> 11;
    int d  = bd & (DIN - 1);

    float A2[NSTATE];
    const float* Ar = A + d * NSTATE;
    #pragma unroll
    for (int n = 0; n < NSTATE; ++n) A2[n] = Ar[n] * L2E;

    float x[NSTATE];
    const float* rec = ws + ((size_t)bd * NCHUNK + c) * REC;
    #pragma unroll
    for (int n = 0; n < NSTATE; ++n) x[n] = rec[n];

    float Dd = Dv[d];
    size_t base = (size_t)bd * SEQ + (size_t)c * LC;
    const float4* u4 = (const float4*)(u + base);
    const float4* d4 = (const float4*)(delta + base);
    const float4* z4 = (const float4*)(z + base);
    float4* o4 = (float4*)(out + base);
    const float* Bp = Bm + (size_t)b * NSTATE * SEQ + (size_t)c * LC;
    const float* Cp = Cm + (size_t)b * NSTATE * SEQ + (size_t)c * LC;

    for (int t4 = 0; t4 < LC / 4; ++t4) {
        float4 uu = u4[t4];
        float4 dd = d4[t4];
        float4 zz = z4[t4];
        float4 yy;
        #pragma unroll
        for (int k = 0; k < 4; ++k) {
            float uv = comp4(uu, k);
            float dt = softplus_f(comp4(dd, k));
            float du = dt * uv;
            int t = t4 * 4 + k;
            float acc = 0.0f;
            #pragma unroll
            for (int n = 0; n < NSTATE; ++n) {
                float dA = __builtin_amdgcn_exp2f(A2[n] * dt);
                x[n] = x[n] * dA + du * Bp[n * SEQ + t];
                acc += x[n] * Cp[n * SEQ + t];
            }
            float y = acc + Dd * uv;
            y = y * silu_f(comp4(zz, k));
            if (k == 0) yy.x = y; else if (k == 1) yy.y = y;
            else if (k == 2) yy.z = y; else yy.w = y;
        }
        o4[t4] = yy;
    }
}

// Fallback if ws is too small: one thread per (b,d), full sequential scan.
__global__ __launch_bounds__(256) void k_simple(
        const float* __restrict__ u, const float* __restrict__ delta,
        const float* __restrict__ A, const float* __restrict__ Bm,
        const float* __restrict__ Cm, const float* __restrict__ Dv,
        const float* __restrict__ z, float* __restrict__ out) {
    int bd = blockIdx.x * 256 + threadIdx.x;
    int b  = bd >> 11;
    int d  = bd & (DIN - 1);

    float A2[NSTATE];
    const float* Ar = A + d * NSTATE;
    #pragma unroll
    for (int n = 0; n < NSTATE; ++n) A2[n] = Ar[n] * L2E;
    float x[NSTATE];
    #pragma unroll
    for (int n = 0; n < NSTATE; ++n) x[n] = 0.0f;

    float Dd = Dv[d];
    size_t base = (size_t)bd * SEQ;
    const float4* u4 = (const float4*)(u + base);
    const float4* d4 = (const float4*)(delta + base);
    const float4* z4 = (const float4*)(z + base);
    float4* o4 = (float4*)(out + base);
    const float* Bp = Bm + (size_t)b * NSTATE * SEQ;
    const float* Cp = Cm + (size_t)b * NSTATE * SEQ;

    for (int t4 = 0; t4 < SEQ / 4; ++t4) {
        float4 uu = u4[t4];
        float4 dd = d4[t4];
        float4 zz = z4[t4];
        float4 yy;
        #pragma unroll
        for (int k = 0; k < 4; ++k) {
            float uv = comp4(uu, k);
            float dt = softplus_f(comp4(dd, k));
            float du = dt * uv;
            int t = t4 * 4 + k;
            float acc = 0.0f;
            #pragma unroll
            for (int n = 0; n < NSTATE; ++n) {
                float dA = __builtin_amdgcn_exp2f(A2[n] * dt);
                x[n] = x[n] * dA + du * Bp[n * SEQ + t];
                acc += x[n] * Cp[n * SEQ + t];
            }
            float y = acc + Dd * uv;
            y = y * silu_f(comp4(zz, k));
            if (k == 0) yy.x = y; else if (k == 1) yy.y = y;
            else if (k == 2) yy.z = y; else yy.w = y;
        }
        o4[t4] = yy;
    }
}

extern "C" void kernel_launch(void* const* d_in, const int* in_sizes, int n_in,
                              void* d_out, int out_size, void* d_ws, size_t ws_size,
                              hipStream_t stream) {
    const float* u     = (const float*)d_in[0];
    const float* delta = (const float*)d_in[1];
    const float* A     = (const float*)d_in[2];
    const float* Bm    = (const float*)d_in[3];
    const float* Cm    = (const float*)d_in[4];
    const float* Dv    = (const float*)d_in[5];
    const float* z     = (const float*)d_in[6];
    float* out = (float*)d_out;

    size_t need = (size_t)NCH * NCHUNK * REC * sizeof(float);
    if (ws_size >= need) {
        float* ws = (float*)d_ws;
        k_pass1<<<NCH * NCHUNK / 256, 256, 0, stream>>>(u, delta, A, Bm, ws);
        k_pass2<<<NCH / 256, 256, 0, stream>>>(A, ws);
        k_pass3<<<NCH * NCHUNK / 256, 256, 0, stream>>>(u, delta, A, Bm, Cm, Dv, z, ws, out);
    } else {
        k_simple<<<NCH / 256, 256, 0, stream>>>(u, delta, A, Bm, Cm, Dv, z, out);
    }
}

// Round 2
// 499.343 us; speedup vs baseline: 1.1961x; 1.1961x over previous
//
#include <hip/hip_runtime.h>

// Mamba selective scan, fp32. u,delta,z:(4,2048,2048) A:(2048,16)
// B,C:(4,16,2048) D:(2048,). Output y:(4,2048,2048).
// 3-pass chunked scan: chunk operator is (S=sum dt, q=local scan), since
// prod_t exp(dt_t*A[n]) == exp(A[n]*sum_t dt_t).
// R2: full-cacheline streaming (16-step tiles, 4x float4 per stream) to kill
// the 4x line-granularity over-fetch seen in R1; SoA workspace layout.

#define BATCHSZ 4
#define DIN 2048
#define NSTATE 16
#define SEQ 2048
#define NCH (BATCHSZ * DIN)     // 8192 channels
#define NCHUNK 16
#define LC (SEQ / NCHUNK)       // 128
#define TT 16                   // time tile: 64B per stream per thread
#define L2E 1.44269504f

__device__ __forceinline__ float softplus_f(float v) {
    float e = __builtin_amdgcn_exp2f(v * L2E);
    return 0.69314718f * __builtin_amdgcn_logf(1.0f + e);
}

__device__ __forceinline__ float silu_f(float v) {
    float s = __builtin_amdgcn_rcpf(1.0f + __builtin_amdgcn_exp2f(-v * L2E));
    return v * s;
}

__device__ __forceinline__ float comp4(const float4& f, int k) {
    return k == 0 ? f.x : k == 1 ? f.y : k == 2 ? f.z : f.w;
}

__device__ __forceinline__ void set4(float4& f, int k, float v) {
    if (k == 0) f.x = v; else if (k == 1) f.y = v; else if (k == 2) f.z = v; else f.w = v;
}

// ws layout (SoA, fully coalesced in every pass):
//   wsq[(n*NCHUNK + c)*NCH + bd]   n in [0,16)
//   wsS[c*NCH + bd]                at offset 16*NCHUNK*NCH

// Pass 1: per (b,d,chunk) local scan from zero state -> (q[16], S)
__global__ __launch_bounds__(256) void k_pass1(
        const float* __restrict__ u, const float* __restrict__ delta,
        const float* __restrict__ A, const float* __restrict__ Bm,
        float* __restrict__ ws) {
    int tid = blockIdx.x * 256 + threadIdx.x;
    int bd = tid & (NCH - 1);        // d fastest -> B loads wave-uniform
    int c  = tid >> 13;              // NCH = 2^13
    int b  = bd >> 11;               // DIN = 2^11
    int d  = bd & (DIN - 1);

    float A2[NSTATE];
    const float* Ar = A + d * NSTATE;
    #pragma unroll
    for (int n = 0; n < NSTATE; ++n) A2[n] = Ar[n] * L2E;

    float x[NSTATE];
    #pragma unroll
    for (int n = 0; n < NSTATE; ++n) x[n] = 0.0f;
    float S = 0.0f;

    size_t base = (size_t)bd * SEQ + (size_t)c * LC;
    const float4* u4 = (const float4*)(u + base);
    const float4* d4 = (const float4*)(delta + base);
    const float* Bp = Bm + (size_t)b * NSTATE * SEQ + (size_t)c * LC;

    for (int tile = 0; tile < LC / TT; ++tile) {
        float4 ub[4], db[4];
        #pragma unroll
        for (int j = 0; j < 4; ++j) { ub[j] = u4[tile * 4 + j]; db[j] = d4[tile * 4 + j]; }
        #pragma unroll
        for (int j = 0; j < 4; ++j) {
            #pragma unroll
            for (int k = 0; k < 4; ++k) {
                float dt = softplus_f(comp4(db[j], k));
                S += dt;
                float du = dt * comp4(ub[j], k);
                int t = tile * TT + j * 4 + k;
                #pragma unroll
                for (int n = 0; n < NSTATE; ++n) {
                    float dA = __builtin_amdgcn_exp2f(A2[n] * dt);
                    x[n] = x[n] * dA + du * Bp[n * SEQ + t];
                }
            }
        }
    }
    float* wsq = ws;
    float* wsS = ws + (size_t)NSTATE * NCHUNK * NCH;
    #pragma unroll
    for (int n = 0; n < NSTATE; ++n) wsq[((size_t)n * NCHUNK + c) * NCH + bd] = x[n];
    wsS[(size_t)c * NCH + bd] = S;
}

// Pass 2: per (b,d) combine chunk operators sequentially; overwrite q with
// the chunk's INITIAL state (prefix), in place.
__global__ __launch_bounds__(256) void k_pass2(
        const float* __restrict__ A, float* __restrict__ ws) {
    int bd = blockIdx.x * 256 + threadIdx.x;
    int d = bd & (DIN - 1);

    float A2[NSTATE];
    const float* Ar = A + d * NSTATE;
    #pragma unroll
    for (int n = 0; n < NSTATE; ++n) A2[n] = Ar[n] * L2E;

    float x[NSTATE];
    #pragma unroll
    for (int n = 0; n < NSTATE; ++n) x[n] = 0.0f;

    float* wsq = ws;
    float* wsS = ws + (size_t)NSTATE * NCHUNK * NCH;

    for (int c = 0; c < NCHUNK; ++c) {
        float S = wsS[(size_t)c * NCH + bd];
        #pragma unroll
        for (int n = 0; n < NSTATE; ++n) {
            float* p = wsq + ((size_t)n * NCHUNK + c) * NCH + bd;
            float q = *p;
            float P = __builtin_amdgcn_exp2f(A2[n] * S);
            *p = x[n];                   // initial state for chunk c
            x[n] = x[n] * P + q;
        }
    }
}

// Pass 3: per (b,d,chunk) rescan from the chunk's initial state; emit y.
__global__ __launch_bounds__(256) void k_pass3(
        const float* __restrict__ u, const float* __restrict__ delta,
        const float* __restrict__ A, const float* __restrict__ Bm,
        const float* __restrict__ Cm, const float* __restrict__ Dv,
        const float* __restrict__ z, const float* __restrict__ ws,
        float* __restrict__ out) {
    int tid = blockIdx.x * 256 + threadIdx.x;
    int bd = tid & (NCH - 1);
    int c  = tid >> 13;
    int b  = bd >> 11;
    int d  = bd & (DIN - 1);

    float A2[NSTATE];
    const float* Ar = A + d * NSTATE;
    #pragma unroll
    for (int n = 0; n < NSTATE; ++n) A2[n] = Ar[n] * L2E;

    const float* wsq = ws;
    float x[NSTATE];
    #pragma unroll
    for (int n = 0; n < NSTATE; ++n)
        x[n] = wsq[((size_t)n * NCHUNK + c) * NCH + bd];

    float Dd = Dv[d];
    size_t base = (size_t)bd * SEQ + (size_t)c * LC;
    const float4* u4 = (const float4*)(u + base);
    const float4* d4 = (const float4*)(delta + base);
    const float4* z4 = (const float4*)(z + base);
    float4* o4 = (float4*)(out + base);
    const float* Bp = Bm + (size_t)b * NSTATE * SEQ + (size_t)c * LC;
    const float* Cp = Cm + (size_t)b * NSTATE * SEQ + (size_t)c * LC;

    for (int tile = 0; tile < LC / TT; ++tile) {
        float4 ub[4], db[4], zb[4];
        #pragma unroll
        for (int j = 0; j < 4; ++j) {
            ub[j] = u4[tile * 4 + j];
            db[j] = d4[tile * 4 + j];
            zb[j] = z4[tile * 4 + j];
        }
        #pragma unroll
        for (int j = 0; j < 4; ++j) {
            float4 yy;
            #pragma unroll
            for (int k = 0; k < 4; ++k) {
                float uv = comp4(ub[j], k);
                float dt = softplus_f(comp4(db[j], k));
                float du = dt * uv;
                int t = tile * TT + j * 4 + k;
                float acc = 0.0f;
                #pragma unroll
                for (int n = 0; n < NSTATE; ++n) {
                    float dA = __builtin_amdgcn_exp2f(A2[n] * dt);
                    x[n] = x[n] * dA + du * Bp[n * SEQ + t];
                    acc += x[n] * Cp[n * SEQ + t];
                }
                float y = acc + Dd * uv;
                y = y * silu_f(comp4(zb[j], k));
                set4(yy, k, y);
            }
            o4[tile * 4 + j] = yy;
        }
    }
}

// Fallback if ws is too small: one thread per (b,d), full sequential scan.
__global__ __launch_bounds__(256) void k_simple(
        const float* __restrict__ u, const float* __restrict__ delta,
        const float* __restrict__ A, const float* __restrict__ Bm,
        const float* __restrict__ Cm, const float* __restrict__ Dv,
        const float* __restrict__ z, float* __restrict__ out) {
    int bd = blockIdx.x * 256 + threadIdx.x;
    int b  = bd >> 11;
    int d  = bd & (DIN - 1);

    float A2[NSTATE];
    const float* Ar = A + d * NSTATE;
    #pragma unroll
    for (int n = 0; n < NSTATE; ++n) A2[n] = Ar[n] * L2E;
    float x[NSTATE];
    #pragma unroll
    for (int n = 0; n < NSTATE; ++n) x[n] = 0.0f;

    float Dd = Dv[d];
    size_t base = (size_t)bd * SEQ;
    const float4* u4 = (const float4*)(u + base);
    const float4* d4 = (const float4*)(delta + base);
    const float4* z4 = (const float4*)(z + base);
    float4* o4 = (float4*)(out + base);
    const float* Bp = Bm + (size_t)b * NSTATE * SEQ;
    const float* Cp = Cm + (size_t)b * NSTATE * SEQ;

    for (int t4 = 0; t4 < SEQ / 4; ++t4) {
        float4 uu = u4[t4];
        float4 dd = d4[t4];
        float4 zz = z4[t4];
        float4 yy;
        #pragma unroll
        for (int k = 0; k < 4; ++k) {
            float uv = comp4(uu, k);
            float dt = softplus_f(comp4(dd, k));
            float du = dt * uv;
            int t = t4 * 4 + k;
            float acc = 0.0f;
            #pragma unroll
            for (int n = 0; n < NSTATE; ++n) {
                float dA = __builtin_amdgcn_exp2f(A2[n] * dt);
                x[n] = x[n] * dA + du * Bp[n * SEQ + t];
                acc += x[n] * Cp[n * SEQ + t];
            }
            float y = acc + Dd * uv;
            y = y * silu_f(comp4(zz, k));
            set4(yy, k, y);
        }
        o4[t4] = yy;
    }
}

extern "C" void kernel_launch(void* const* d_in, const int* in_sizes, int n_in,
                              void* d_out, int out_size, void* d_ws, size_t ws_size,
                              hipStream_t stream) {
    const float* u     = (const float*)d_in[0];
    const float* delta = (const float*)d_in[1];
    const float* A     = (const float*)d_in[2];
    const float* Bm    = (const float*)d_in[3];
    const float* Cm    = (const float*)d_in[4];
    const float* Dv    = (const float*)d_in[5];
    const float* z     = (const float*)d_in[6];
    float* out = (float*)d_out;

    size_t need = (size_t)(NSTATE + 1) * NCHUNK * NCH * sizeof(float);
    if (ws_size >= need) {
        float* ws = (float*)d_ws;
        k_pass1<<<NCH * NCHUNK / 256, 256, 0, stream>>>(u, delta, A, Bm, ws);
        k_pass2<<<NCH / 256, 256, 0, stream>>>(A, ws);
        k_pass3<<<NCH * NCHUNK / 256, 256, 0, stream>>>(u, delta, A, Bm, Cm, Dv, z, ws, out);
    } else {
        k_simple<<<NCH / 256, 256, 0, stream>>>(u, delta, A, Bm, Cm, Dv, z, out);
    }
}

// Round 3
// 464.743 us; speedup vs baseline: 1.2851x; 1.0744x over previous
//
#include <hip/hip_runtime.h>

// Mamba selective scan, fp32. u,delta,z:(4,2048,2048) A:(2048,16)
// B,C:(4,16,2048) D:(2048,). Output y:(4,2048,2048).
// 3-pass chunked scan: chunk operator is (S=sum dt, q=local scan), since
// prod_t exp(dt_t*A[n]) == exp(A[n]*sum_t dt_t).
// R3: 32-step tiles (128 B = full L2 line per thread per stream, kills the
// remaining 2x over-fetch), b/c derived from blockIdx so B/C loads are
// provably wave-uniform (scalar pipe), NCHUNK=32 for occupancy.

#define BATCHSZ 4
#define DIN 2048
#define NSTATE 16
#define SEQ 2048
#define NCH (BATCHSZ * DIN)     // 8192 channels
#define TT 32                   // time tile: 128 B per stream per thread
#define L2E 1.44269504f

__device__ __forceinline__ float softplus_f(float v) {
    float e = __builtin_amdgcn_exp2f(v * L2E);
    return 0.69314718f * __builtin_amdgcn_logf(1.0f + e);
}

__device__ __forceinline__ float silu_f(float v) {
    float s = __builtin_amdgcn_rcpf(1.0f + __builtin_amdgcn_exp2f(-v * L2E));
    return v * s;
}

__device__ __forceinline__ float comp4(const float4& f, int k) {
    return k == 0 ? f.x : k == 1 ? f.y : k == 2 ? f.z : f.w;
}

__device__ __forceinline__ void set4(float4& f, int k, float v) {
    if (k == 0) f.x = v; else if (k == 1) f.y = v; else if (k == 2) f.z = v; else f.w = v;
}

// ws layout (SoA, fully coalesced in every pass):
//   wsq[(n*NC + c)*NCH + bd]   n in [0,16)
//   wsS[c*NCH + bd]            at offset 16*NC*NCH

// Pass 1: per (b,d,chunk) local scan from zero state -> (q[16], S)
template<int NC>
__global__ __launch_bounds__(256, 3) void k_pass1(
        const float* __restrict__ u, const float* __restrict__ delta,
        const float* __restrict__ A, const float* __restrict__ Bm,
        float* __restrict__ ws) {
    constexpr int LC = SEQ / NC;
    constexpr int DB = DIN / 256;
    int blk = blockIdx.x;
    int b = (blk / DB) % BATCHSZ;           // wave-uniform (from blockIdx)
    int c = blk / (DB * BATCHSZ);           // wave-uniform
    int d = (blk % DB) * 256 + threadIdx.x;
    int bd = b * DIN + d;

    float A2[NSTATE];
    const float* Ar = A + d * NSTATE;
    #pragma unroll
    for (int n = 0; n < NSTATE; ++n) A2[n] = Ar[n] * L2E;

    float x[NSTATE];
    #pragma unroll
    for (int n = 0; n < NSTATE; ++n) x[n] = 0.0f;
    float S = 0.0f;

    size_t base = (size_t)bd * SEQ + (size_t)c * LC;
    const float4* u4 = (const float4*)(u + base);
    const float4* d4 = (const float4*)(delta + base);
    const float* Bp = Bm + (size_t)b * NSTATE * SEQ + (size_t)c * LC;  // uniform

    for (int tile = 0; tile < LC / TT; ++tile) {
        float4 ub[8], db[8];
        #pragma unroll
        for (int j = 0; j < 8; ++j) { ub[j] = u4[tile * 8 + j]; db[j] = d4[tile * 8 + j]; }
        #pragma unroll
        for (int j = 0; j < 8; ++j) {
            #pragma unroll
            for (int k = 0; k < 4; ++k) {
                float dt = softplus_f(comp4(db[j], k));
                S += dt;
                float du = dt * comp4(ub[j], k);
                int t = tile * TT + j * 4 + k;
                #pragma unroll
                for (int n = 0; n < NSTATE; ++n) {
                    float dA = __builtin_amdgcn_exp2f(A2[n] * dt);
                    x[n] = x[n] * dA + du * Bp[n * SEQ + t];
                }
            }
        }
    }
    float* wsq = ws;
    float* wsS = ws + (size_t)NSTATE * NC * NCH;
    #pragma unroll
    for (int n = 0; n < NSTATE; ++n) wsq[((size_t)n * NC + c) * NCH + bd] = x[n];
    wsS[(size_t)c * NCH + bd] = S;
}

// Pass 2: per (b,d) combine chunk operators sequentially; overwrite q with
// the chunk's INITIAL state (prefix), in place.
template<int NC>
__global__ __launch_bounds__(256) void k_pass2(
        const float* __restrict__ A, float* __restrict__ ws) {
    int bd = blockIdx.x * 256 + threadIdx.x;
    int d = bd & (DIN - 1);

    float A2[NSTATE];
    const float* Ar = A + d * NSTATE;
    #pragma unroll
    for (int n = 0; n < NSTATE; ++n) A2[n] = Ar[n] * L2E;

    float x[NSTATE];
    #pragma unroll
    for (int n = 0; n < NSTATE; ++n) x[n] = 0.0f;

    float* wsq = ws;
    float* wsS = ws + (size_t)NSTATE * NC * NCH;

    for (int c = 0; c < NC; ++c) {
        float S = wsS[(size_t)c * NCH + bd];
        #pragma unroll
        for (int n = 0; n < NSTATE; ++n) {
            float* p = wsq + ((size_t)n * NC + c) * NCH + bd;
            float q = *p;
            float P = __builtin_amdgcn_exp2f(A2[n] * S);
            *p = x[n];                   // initial state for chunk c
            x[n] = x[n] * P + q;
        }
    }
}

// Pass 3: per (b,d,chunk) rescan from the chunk's initial state; emit y.
template<int NC>
__global__ __launch_bounds__(256, 3) void k_pass3(
        const float* __restrict__ u, const float* __restrict__ delta,
        const float* __restrict__ A, const float* __restrict__ Bm,
        const float* __restrict__ Cm, const float* __restrict__ Dv,
        const float* __restrict__ z, const float* __restrict__ ws,
        float* __restrict__ out) {
    constexpr int LC = SEQ / NC;
    constexpr int DB = DIN / 256;
    int blk = blockIdx.x;
    int b = (blk / DB) % BATCHSZ;           // wave-uniform
    int c = blk / (DB * BATCHSZ);           // wave-uniform
    int d = (blk % DB) * 256 + threadIdx.x;
    int bd = b * DIN + d;

    float A2[NSTATE];
    const float* Ar = A + d * NSTATE;
    #pragma unroll
    for (int n = 0; n < NSTATE; ++n) A2[n] = Ar[n] * L2E;

    const float* wsq = ws;
    float x[NSTATE];
    #pragma unroll
    for (int n = 0; n < NSTATE; ++n)
        x[n] = wsq[((size_t)n * NC + c) * NCH + bd];

    float Dd = Dv[d];
    size_t base = (size_t)bd * SEQ + (size_t)c * LC;
    const float4* u4 = (const float4*)(u + base);
    const float4* d4 = (const float4*)(delta + base);
    const float4* z4 = (const float4*)(z + base);
    float4* o4 = (float4*)(out + base);
    const float* Bp = Bm + (size_t)b * NSTATE * SEQ + (size_t)c * LC;  // uniform
    const float* Cp = Cm + (size_t)b * NSTATE * SEQ + (size_t)c * LC;  // uniform

    for (int tile = 0; tile < LC / TT; ++tile) {
        float4 ub[8], db[8];
        #pragma unroll
        for (int j = 0; j < 8; ++j) { ub[j] = u4[tile * 8 + j]; db[j] = d4[tile * 8 + j]; }
        float4 yy[8];   // pre-gate y; ub/db die as yy is born (flat liveness)
        #pragma unroll
        for (int j = 0; j < 8; ++j) {
            #pragma unroll
            for (int k = 0; k < 4; ++k) {
                float uv = comp4(ub[j], k);
                float dt = softplus_f(comp4(db[j], k));
                float du = dt * uv;
                int t = tile * TT + j * 4 + k;
                float acc = 0.0f;
                #pragma unroll
                for (int n = 0; n < NSTATE; ++n) {
                    float dA = __builtin_amdgcn_exp2f(A2[n] * dt);
                    x[n] = x[n] * dA + du * Bp[n * SEQ + t];
                    acc += x[n] * Cp[n * SEQ + t];
                }
                set4(yy[j], k, acc + Dd * uv);
            }
        }
        float4 zb[8];
        #pragma unroll
        for (int j = 0; j < 8; ++j) zb[j] = z4[tile * 8 + j];
        #pragma unroll
        for (int j = 0; j < 8; ++j) {
            float4 oo;
            #pragma unroll
            for (int k = 0; k < 4; ++k)
                set4(oo, k, comp4(yy[j], k) * silu_f(comp4(zb[j], k)));
            o4[tile * 8 + j] = oo;
        }
    }
}

// Fallback if ws is too small: one thread per (b,d), full sequential scan.
__global__ __launch_bounds__(256) void k_simple(
        const float* __restrict__ u, const float* __restrict__ delta,
        const float* __restrict__ A, const float* __restrict__ Bm,
        const float* __restrict__ Cm, const float* __restrict__ Dv,
        const float* __restrict__ z, float* __restrict__ out) {
    int bd = blockIdx.x * 256 + threadIdx.x;
    int b  = bd >> 11;
    int d  = bd & (DIN - 1);

    float A2[NSTATE];
    const float* Ar = A + d * NSTATE;
    #pragma unroll
    for (int n = 0; n < NSTATE; ++n) A2[n] = Ar[n] * L2E;
    float x[NSTATE];
    #pragma unroll
    for (int n = 0; n < NSTATE; ++n) x[n] = 0.0f;

    float Dd = Dv[d];
    size_t base = (size_t)bd * SEQ;
    const float4* u4 = (const float4*)(u + base);
    const float4* d4 = (const float4*)(delta + base);
    const float4* z4 = (const float4*)(z + base);
    float4* o4 = (float4*)(out + base);
    const float* Bp = Bm + (size_t)b * NSTATE * SEQ;
    const float* Cp = Cm + (size_t)b * NSTATE * SEQ;

    for (int t4 = 0; t4 < SEQ / 4; ++t4) {
        float4 uu = u4[t4];
        float4 dd = d4[t4];
        float4 zz = z4[t4];
        float4 yy;
        #pragma unroll
        for (int k = 0; k < 4; ++k) {
            float uv = comp4(uu, k);
            float dt = softplus_f(comp4(dd, k));
            float du = dt * uv;
            int t = t4 * 4 + k;
            float acc = 0.0f;
            #pragma unroll
            for (int n = 0; n < NSTATE; ++n) {
                float dA = __builtin_amdgcn_exp2f(A2[n] * dt);
                x[n] = x[n] * dA + du * Bp[n * SEQ + t];
                acc += x[n] * Cp[n * SEQ + t];
            }
            float y = acc + Dd * uv;
            y = y * silu_f(comp4(zz, k));
            set4(yy, k, y);
        }
        o4[t4] = yy;
    }
}

template<int NC>
static void launch_chunked(const float* u, const float* delta, const float* A,
                           const float* Bm, const float* Cm, const float* Dv,
                           const float* z, float* ws, float* out, hipStream_t stream) {
    k_pass1<NC><<<NCH * NC / 256, 256, 0, stream>>>(u, delta, A, Bm, ws);
    k_pass2<NC><<<NCH / 256, 256, 0, stream>>>(A, ws);
    k_pass3<NC><<<NCH * NC / 256, 256, 0, stream>>>(u, delta, A, Bm, Cm, Dv, z, ws, out);
}

extern "C" void kernel_launch(void* const* d_in, const int* in_sizes, int n_in,
                              void* d_out, int out_size, void* d_ws, size_t ws_size,
                              hipStream_t stream) {
    const float* u     = (const float*)d_in[0];
    const float* delta = (const float*)d_in[1];
    const float* A     = (const float*)d_in[2];
    const float* Bm    = (const float*)d_in[3];
    const float* Cm    = (const float*)d_in[4];
    const float* Dv    = (const float*)d_in[5];
    const float* z     = (const float*)d_in[6];
    float* out = (float*)d_out;
    float* ws = (float*)d_ws;

    size_t need32 = (size_t)(NSTATE + 1) * 32 * NCH * sizeof(float);
    size_t need16 = (size_t)(NSTATE + 1) * 16 * NCH * sizeof(float);
    if (ws_size >= need32) {
        launch_chunked<32>(u, delta, A, Bm, Cm, Dv, z, ws, out, stream);
    } else if (ws_size >= need16) {
        launch_chunked<16>(u, delta, A, Bm, Cm, Dv, z, ws, out, stream);
    } else {
        k_simple<<<NCH / 256, 256, 0, stream>>>(u, delta, A, Bm, Cm, Dv, z, out);
    }
}